// Round 7
// baseline (589.128 us; speedup 1.0000x reference)
//
#include <hip/hip_runtime.h>

#define BB 4
#define LL 2048
#define DD 512
#define HH 8
#define NLAYER 2

typedef __attribute__((ext_vector_type(8))) short short8;
typedef __attribute__((ext_vector_type(4))) float floatx4;
typedef __attribute__((ext_vector_type(16))) float floatx16;

union U4S8 { uint4 u4; short8 s8; unsigned int u[4]; };

__device__ __forceinline__ unsigned short f2bf(float f) {
  unsigned int u = __float_as_uint(f);
  u += 0x7fffu + ((u >> 16) & 1u);
  return (unsigned short)(u >> 16);
}
__device__ __forceinline__ float bf2f(unsigned short s) {
  return __uint_as_float(((unsigned int)s) << 16);
}
// pack two fp32 -> bf16 pair, round-half-up
__device__ __forceinline__ unsigned int pack_bf16(float a0, float a1) {
  unsigned int u0 = __float_as_uint(a0) + 0x8000u;
  unsigned int u1 = __float_as_uint(a1) + 0x8000u;
  return __builtin_amdgcn_perm(u1, u0, 0x07060302u);
}
// truncating pack (1 op); bias cancels when lsum uses same truncated values
__device__ __forceinline__ unsigned int pack_bf16_trunc(float a0, float a1) {
  return __builtin_amdgcn_perm(__float_as_uint(a1), __float_as_uint(a0), 0x07060302u);
}
__device__ __forceinline__ float fast_exp2(float x) {
#if __has_builtin(__builtin_amdgcn_exp2f)
  return __builtin_amdgcn_exp2f(x);
#else
  return exp2f(x);
#endif
}
__device__ __forceinline__ float fast_exp(float x) {
  return fast_exp2(x * 1.442695040888963f);
}

// ---------------- batched weight transpose fp32 (512 x C) -> bf16 (C x 512) ----------------
struct TJob { const float* src; unsigned short* dst; int C; int il; };
struct TJobs { TJob j[12]; };

__global__ __launch_bounds__(256) void transpose_all_kernel(TJobs jobs) {
  TJob jb = jobs.j[blockIdx.z];
  int c0 = blockIdx.x * 32;
  if (c0 >= jb.C) return;
  const int R = 512;
  __shared__ float t[32][33];
  int r0 = blockIdx.y * 32;
#pragma unroll
  for (int i = 0; i < 4; i++) {
    int idx = threadIdx.x + i * 256;
    t[idx >> 5][idx & 31] = jb.src[(size_t)(r0 + (idx >> 5)) * jb.C + c0 + (idx & 31)];
  }
  __syncthreads();
#pragma unroll
  for (int i = 0; i < 4; i++) {
    int idx = threadIdx.x + i * 256;
    int cc = idx >> 5, rr = idx & 31;
    int c = c0 + cc;
    int orow = jb.il ? ((c < 512) ? 2 * c : 2 * (c - 512) + 1) : c;
    jb.dst[(size_t)orow * R + r0 + rr] = f2bf(t[rr][cc]);
  }
}

// ---------------- LayerNorm (D=512), block per row ----------------
__global__ __launch_bounds__(256) void ln_kernel(
    const float* __restrict__ x, const float* __restrict__ w, const float* __restrict__ b,
    unsigned short* __restrict__ outB, float* __restrict__ outF) {
  int row = blockIdx.x;
  const float* xr = x + (size_t)row * DD;
  int tid = threadIdx.x;
  float2 v = *(const float2*)(xr + tid * 2);
  float s = v.x + v.y;
  float ss = v.x * v.x + v.y * v.y;
#pragma unroll
  for (int off = 1; off < 64; off <<= 1) {
    s += __shfl_xor(s, off);
    ss += __shfl_xor(ss, off);
  }
  __shared__ float red[2][4];
  int wave = tid >> 6, lane = tid & 63;
  if (lane == 0) { red[0][wave] = s; red[1][wave] = ss; }
  __syncthreads();
  s = red[0][0] + red[0][1] + red[0][2] + red[0][3];
  ss = red[1][0] + red[1][1] + red[1][2] + red[1][3];
  float mu = s * (1.0f / DD);
  float var = ss * (1.0f / DD) - mu * mu;
  float inv = rsqrtf(var + 1e-5f);
#pragma unroll
  for (int j = 0; j < 2; j++) {
    int c = tid * 2 + j;
    float val = (((j == 0) ? v.x : v.y) - mu) * inv * w[c] + b[c];
    if (outB) outB[(size_t)row * DD + c] = f2bf(val);
    if (outF) outF[(size_t)row * DD + c] = val;
  }
}

// ---------------- GEMM: C[MxN] = A[MxK](bf16) * Bt[NxK](bf16)^T ----------------
// 128x128 tile, BK=32, global_load_lds(16B) with XOR-granule swizzle (m97-style).
// QKV mode (vtp != null, N=1536): n0>=1024 tiles (V) stored TRANSPOSED to vtp;
// n0<1024 tiles (Q,K) get RoPE applied in-register ((d,d+32) = reg pairs (j,j+2));
// Q additionally pre-scaled by 0.125*log2e for the attn exp2 path.
__global__ __launch_bounds__(256) void gemm128_kernel(
    const unsigned short* __restrict__ A, const unsigned short* __restrict__ Bt,
    float* __restrict__ outF, unsigned short* __restrict__ outB,
    const float* __restrict__ res, int M, int N, int K,
    unsigned short* __restrict__ vtp,
    const float* __restrict__ pcos, const float* __restrict__ psin) {
  __shared__ alignas(16) unsigned short As[128 * 32];
  __shared__ alignas(16) unsigned short Bs[128 * 32];
  const int tid = threadIdx.x;
  const int wave = tid >> 6, lane = tid & 63;
  const int l16 = lane & 15, quad = lane >> 4;
  const int wm = wave & 1, wn = wave >> 1;
  const int m0 = blockIdx.y * 128, n0 = blockIdx.x * 128;

  floatx4 acc[4][4];
#pragma unroll
  for (int i = 0; i < 4; i++)
#pragma unroll
    for (int j = 0; j < 4; j++)
#pragma unroll
      for (int r = 0; r < 4; r++) acc[i][j][r] = 0.f;

  const int grow = lane >> 2;
  const int gg = lane & 3;

  for (int kt = 0; kt < K; kt += 32) {
#pragma unroll
    for (int i = 0; i < 2; i++) {
      int rb = (wave * 2 + i) * 16;
      int row = rb + grow;
      int gsw = gg ^ (row & 3);
      const unsigned short* srcA = A + (size_t)(m0 + row) * K + kt + gsw * 8;
      const unsigned short* srcB = Bt + (size_t)(n0 + row) * K + kt + gsw * 8;
      __builtin_amdgcn_global_load_lds(
          (const __attribute__((address_space(1))) unsigned int*)srcA,
          (__attribute__((address_space(3))) unsigned int*)(As + rb * 32), 16, 0, 0);
      __builtin_amdgcn_global_load_lds(
          (const __attribute__((address_space(1))) unsigned int*)srcB,
          (__attribute__((address_space(3))) unsigned int*)(Bs + rb * 32), 16, 0, 0);
    }
    __syncthreads();
    short8 af[4], bf[4];
#pragma unroll
    for (int i = 0; i < 4; i++) {
      int rowa = wm * 64 + i * 16 + l16;
      af[i] = *(const short8*)&As[rowa * 32 + (quad ^ (rowa & 3)) * 8];
      int rowb = wn * 64 + i * 16 + l16;
      bf[i] = *(const short8*)&Bs[rowb * 32 + (quad ^ (rowb & 3)) * 8];
    }
#pragma unroll
    for (int i = 0; i < 4; i++)
#pragma unroll
      for (int j = 0; j < 4; j++)
        acc[i][j] = __builtin_amdgcn_mfma_f32_16x16x32_bf16(af[i], bf[j], acc[i][j], 0, 0, 0);
    __syncthreads();
  }
  if (vtp && n0 >= 1024) {
    // transposed V store: 4 consecutive seq rows per 8B chunk, same d
#pragma unroll
    for (int i = 0; i < 4; i++)
#pragma unroll
      for (int j = 0; j < 4; j++) {
        int cg = (n0 - 1024) + wn * 64 + j * 16 + l16;  // 0..511
        int hh = cg >> 6, dd = cg & 63;
        int seq0 = m0 + wm * 64 + i * 16 + quad * 4;
        int bI = seq0 >> 11, ls = seq0 & 2047;
        unsigned short* dst = vtp + ((size_t)(bI * 8 + hh) * 64 + dd) * 2048 + ls;
        uint2 w;
        w.x = pack_bf16(acc[i][j][0], acc[i][j][1]);
        w.y = pack_bf16(acc[i][j][2], acc[i][j][3]);
        *(uint2*)dst = w;
      }
    return;
  }
  if (vtp) {
    // RoPE on Q (n0<512, also pre-scaled) and K (512<=n0<1024)
    const float QSCALE = 0.125f * 1.442695040888963f;
    const float osc = (n0 < 512) ? QSCALE : 1.0f;
#pragma unroll
    for (int i = 0; i < 4; i++)
#pragma unroll
      for (int r = 0; r < 4; r++) {
        int row = m0 + wm * 64 + i * 16 + quad * 4 + r;
        int t = row & 2047;
        const float* cr = pcos + (size_t)t * 512;
        const float* sr = psin + (size_t)t * 512;
#pragma unroll
        for (int jj = 0; jj < 2; jj++) {
          int colL = n0 + wn * 64 + jj * 16 + l16;
          int cL = colL & 511, cH = cL + 32;
          float aL = acc[i][jj][r], aH = acc[i][jj + 2][r];
          float outL = (aL * cr[cL] - aH * sr[cL]) * osc;
          float outH = (aH * cr[cH] + aL * sr[cH]) * osc;
          size_t base = (size_t)row * N + colL;
          outB[base] = f2bf(outL);
          outB[base + 32] = f2bf(outH);
        }
      }
    return;
  }
#pragma unroll
  for (int i = 0; i < 4; i++)
#pragma unroll
    for (int j = 0; j < 4; j++)
#pragma unroll
      for (int r = 0; r < 4; r++) {
        int row = m0 + wm * 64 + i * 16 + quad * 4 + r;
        int col = n0 + wn * 64 + j * 16 + l16;
        size_t idx = (size_t)row * N + col;
        float val = acc[i][j][r];
        if (res) val += res[idx];
        if (outF) outF[idx] = val;
        if (outB) outB[idx] = f2bf(val);
      }
}

// ---------------- GEMM 128x64 tile (for N=512 outputs: grid 512 -> 2 blocks/CU) ----------------
__global__ __launch_bounds__(256) void gemm64n_kernel(
    const unsigned short* __restrict__ A, const unsigned short* __restrict__ Bt,
    float* __restrict__ outF, const float* __restrict__ res, int M, int N, int K) {
  __shared__ alignas(16) unsigned short As[128 * 32];
  __shared__ alignas(16) unsigned short Bs[64 * 32];
  const int tid = threadIdx.x;
  const int wave = tid >> 6, lane = tid & 63;
  const int l16 = lane & 15, quad = lane >> 4;
  const int m0 = blockIdx.y * 128, n0 = blockIdx.x * 64;

  floatx4 acc[2][4];
#pragma unroll
  for (int i = 0; i < 2; i++)
#pragma unroll
    for (int j = 0; j < 4; j++)
#pragma unroll
      for (int r = 0; r < 4; r++) acc[i][j][r] = 0.f;

  const int grow = lane >> 2;
  const int gg = lane & 3;

  for (int kt = 0; kt < K; kt += 32) {
#pragma unroll
    for (int i = 0; i < 3; i++) {
      int id = wave * 3 + i;
      if (id < 8) {
        int rb = id * 16;
        int row = rb + grow;
        int gsw = gg ^ (row & 3);
        const unsigned short* srcA = A + (size_t)(m0 + row) * K + kt + gsw * 8;
        __builtin_amdgcn_global_load_lds(
            (const __attribute__((address_space(1))) unsigned int*)srcA,
            (__attribute__((address_space(3))) unsigned int*)(As + rb * 32), 16, 0, 0);
      } else {
        int rb = (id - 8) * 16;
        int row = rb + grow;
        int gsw = gg ^ (row & 3);
        const unsigned short* srcB = Bt + (size_t)(n0 + row) * K + kt + gsw * 8;
        __builtin_amdgcn_global_load_lds(
            (const __attribute__((address_space(1))) unsigned int*)srcB,
            (__attribute__((address_space(3))) unsigned int*)(Bs + rb * 32), 16, 0, 0);
      }
    }
    __syncthreads();
    short8 af[2], bfr[4];
#pragma unroll
    for (int i = 0; i < 2; i++) {
      int rowa = wave * 32 + i * 16 + l16;
      af[i] = *(const short8*)&As[rowa * 32 + (quad ^ (rowa & 3)) * 8];
    }
#pragma unroll
    for (int j = 0; j < 4; j++) {
      int rowb = j * 16 + l16;
      bfr[j] = *(const short8*)&Bs[rowb * 32 + (quad ^ (rowb & 3)) * 8];
    }
#pragma unroll
    for (int i = 0; i < 2; i++)
#pragma unroll
      for (int j = 0; j < 4; j++)
        acc[i][j] = __builtin_amdgcn_mfma_f32_16x16x32_bf16(af[i], bfr[j], acc[i][j], 0, 0, 0);
    __syncthreads();
  }
#pragma unroll
  for (int i = 0; i < 2; i++)
#pragma unroll
    for (int j = 0; j < 4; j++)
#pragma unroll
      for (int r = 0; r < 4; r++) {
        int row = m0 + wave * 32 + i * 16 + quad * 4 + r;
        int col = n0 + j * 16 + l16;
        size_t idx = (size_t)row * N + col;
        float val = acc[i][j][r];
        if (res) val += res[idx];
        outF[idx] = val;
      }
}

// ---------------- GEMM + fused SwiGLU epilogue ----------------
__global__ __launch_bounds__(256) void gemm_swiglu_kernel(
    const unsigned short* __restrict__ A, const unsigned short* __restrict__ Bt,
    unsigned short* __restrict__ gout, int M, int N, int K) {
  __shared__ alignas(16) unsigned short As[128 * 32];
  __shared__ alignas(16) unsigned short Bs[128 * 32];
  const int tid = threadIdx.x;
  const int wave = tid >> 6, lane = tid & 63;
  const int l16 = lane & 15, quad = lane >> 4;
  const int wm = wave & 1, wn = wave >> 1;
  const int m0 = blockIdx.y * 128, n0 = blockIdx.x * 128;
  floatx4 acc[4][4];
#pragma unroll
  for (int i = 0; i < 4; i++)
#pragma unroll
    for (int j = 0; j < 4; j++)
#pragma unroll
      for (int r = 0; r < 4; r++) acc[i][j][r] = 0.f;
  const int grow = lane >> 2;
  const int gg = lane & 3;
  for (int kt = 0; kt < K; kt += 32) {
#pragma unroll
    for (int i = 0; i < 2; i++) {
      int rb = (wave * 2 + i) * 16;
      int row = rb + grow;
      int gsw = gg ^ (row & 3);
      const unsigned short* srcA = A + (size_t)(m0 + row) * K + kt + gsw * 8;
      const unsigned short* srcB = Bt + (size_t)(n0 + row) * K + kt + gsw * 8;
      __builtin_amdgcn_global_load_lds(
          (const __attribute__((address_space(1))) unsigned int*)srcA,
          (__attribute__((address_space(3))) unsigned int*)(As + rb * 32), 16, 0, 0);
      __builtin_amdgcn_global_load_lds(
          (const __attribute__((address_space(1))) unsigned int*)srcB,
          (__attribute__((address_space(3))) unsigned int*)(Bs + rb * 32), 16, 0, 0);
    }
    __syncthreads();
    short8 af[4], bf[4];
#pragma unroll
    for (int i = 0; i < 4; i++) {
      int rowa = wm * 64 + i * 16 + l16;
      af[i] = *(const short8*)&As[rowa * 32 + (quad ^ (rowa & 3)) * 8];
      int rowb = wn * 64 + i * 16 + l16;
      bf[i] = *(const short8*)&Bs[rowb * 32 + (quad ^ (rowb & 3)) * 8];
    }
#pragma unroll
    for (int i = 0; i < 4; i++)
#pragma unroll
      for (int j = 0; j < 4; j++)
        acc[i][j] = __builtin_amdgcn_mfma_f32_16x16x32_bf16(af[i], bf[j], acc[i][j], 0, 0, 0);
    __syncthreads();
  }
  const int Nh = N >> 1;
#pragma unroll
  for (int i = 0; i < 4; i++)
#pragma unroll
    for (int j = 0; j < 4; j++)
#pragma unroll
      for (int r = 0; r < 4; r++) {
        float val = acc[i][j][r];
        float part = __shfl_xor(val, 1);
        float x1 = (l16 & 1) ? part : val;
        float x2 = (l16 & 1) ? val : part;
        float g = x1 / (1.f + fast_exp(-x1)) * x2;
        if (!(l16 & 1)) {
          int row = m0 + wm * 64 + i * 16 + quad * 4 + r;
          int gcol = (n0 + wn * 64 + j * 16 + l16) >> 1;
          gout[(size_t)row * Nh + gcol] = f2bf(g);
        }
      }
}

// ---------------- attention: S^T = K Q^T via 32x32x16 MFMA ----------------
// KT=128 keys/stage (16 barriers vs 32), double-buffered; the proven 64-key
// body runs twice per stage. Q comes pre-scaled by 0.125*log2e (gemm epilogue).
__global__ __launch_bounds__(256, 2) void attn_kernel(
    const unsigned short* __restrict__ qkv, const unsigned short* __restrict__ vtp,
    const float* __restrict__ mask, unsigned short* __restrict__ ctx) {
  __shared__ alignas(16) unsigned short Ks[2][128][72];
  __shared__ alignas(16) unsigned short Vs[2][64][136];
  const int tid = threadIdx.x;
  const int wave = tid >> 6, lane = tid & 63;
  const int l5 = lane & 31, b5 = lane >> 5;
  const int b = blockIdx.z, h = blockIdx.y;
  const int q0 = blockIdx.x * 128 + wave * 32;
  const int bh = b * 8 + h;

  short8 qf[4];
  {
    const unsigned short* qp = qkv + (size_t)(b * LL + q0 + l5) * 1536 + h * 64 + b5 * 8;
#pragma unroll
    for (int t = 0; t < 4; t++) {
      U4S8 u;
      u.u4 = *(const uint4*)(qp + t * 16);
      qf[t] = u.s8;
    }
  }
  short8 bones = {0, 0, 0, 0, 0, 0, 0, 0};
  if (b5 == 0) bones[0] = (short)0x3F80;
  short8 onesA;
#pragma unroll
  for (int e = 0; e < 8; e++) onesA[e] = (short)0x3F80;

  floatx16 O[2], Lacc;
#pragma unroll
  for (int a = 0; a < 2; a++)
#pragma unroll
    for (int r = 0; r < 16; r++) O[a][r] = 0.f;
#pragma unroll
  for (int r = 0; r < 16; r++) Lacc[r] = 0.f;

  // staging: K 128 rows x 64 d (64B/thread), V 64 d-rows x 128 keys (64B/thread)
  const int krow = tid >> 1, kc = (tid & 1) * 32;
  const int vrow = tid >> 2, vc = (tid & 3) * 32;
  const unsigned short* kbase = qkv + (size_t)(b * LL + krow) * 1536 + 512 + h * 64 + kc;
  const unsigned short* vbase = vtp + (size_t)(bh * 64 + vrow) * 2048 + vc;

  uint4 kr[4], vr[4];
#pragma unroll
  for (int g = 0; g < 4; g++) {
    kr[g] = *(const uint4*)(kbase + g * 8);
    vr[g] = *(const uint4*)(vbase + g * 8);
  }

  for (int it = 0; it < 16; it++) {
    const int buf = it & 1;
    const int t0 = it * 128;
#pragma unroll
    for (int g = 0; g < 4; g++) {
      *(uint4*)&Ks[buf][krow][kc + g * 8] = kr[g];
      *(uint4*)&Vs[buf][vrow][vc + g * 8] = vr[g];
    }
    __syncthreads();
    if (it < 15) {
      const unsigned short* kn = kbase + (size_t)(t0 + 128) * 1536;
      const unsigned short* vn = vbase + t0 + 128;
#pragma unroll
      for (int g = 0; g < 4; g++) {
        kr[g] = *(const uint4*)(kn + g * 8);
        vr[g] = *(const uint4*)(vn + g * 8);
      }
    }
#pragma unroll
    for (int half = 0; half < 2; half++) {
      const int kb = half * 64;
      float mk0 = mask[b * LL + t0 + kb + l5];
      float mk1 = mask[b * LL + t0 + kb + 32 + l5];
      short8 kf[2][4];
#pragma unroll
      for (int ms = 0; ms < 2; ms++)
#pragma unroll
        for (int t = 0; t < 4; t++)
          kf[ms][t] = *(const short8*)&Ks[buf][kb + ms * 32 + l5][t * 16 + b5 * 8];

      floatx16 s0, s1;
#pragma unroll
      for (int r = 0; r < 16; r++) { s0[r] = 0.f; s1[r] = 0.f; }
#pragma unroll
      for (int t = 0; t < 4; t++) {
        s0 = __builtin_amdgcn_mfma_f32_32x32x16_bf16(kf[0][t], qf[t], s0, 0, 0, 0);
        s1 = __builtin_amdgcn_mfma_f32_32x32x16_bf16(kf[1][t], qf[t], s1, 0, 0, 0);
      }
      if (__any(mk0 != 0.0f || mk1 != 0.0f)) {
        short8 am0 = {0, 0, 0, 0, 0, 0, 0, 0}, am1 = {0, 0, 0, 0, 0, 0, 0, 0};
        if (b5 == 0) {
          am0[0] = (short)f2bf(1.442695040888963f * mk0);
          am1[0] = (short)f2bf(1.442695040888963f * mk1);
        }
        s0 = __builtin_amdgcn_mfma_f32_32x32x16_bf16(am0, bones, s0, 0, 0, 0);
        s1 = __builtin_amdgcn_mfma_f32_32x32x16_bf16(am1, bones, s1, 0, 0, 0);
      }

      unsigned int pk[2][8];
#pragma unroll
      for (int i = 0; i < 8; i++) {
        pk[0][i] = pack_bf16_trunc(fast_exp2(s0[2 * i]), fast_exp2(s0[2 * i + 1]));
        pk[1][i] = pack_bf16_trunc(fast_exp2(s1[2 * i]), fast_exp2(s1[2 * i + 1]));
      }
#pragma unroll
      for (int ms = 0; ms < 2; ms++) {
#pragma unroll
        for (int kp = 0; kp < 2; kp++) {
          unsigned int se0 = b5 ? pk[ms][4 * kp] : pk[ms][4 * kp + 2];
          unsigned int se1 = b5 ? pk[ms][4 * kp + 1] : pk[ms][4 * kp + 3];
          unsigned int w0 = (unsigned int)__shfl_xor((int)se0, 32);
          unsigned int w1 = (unsigned int)__shfl_xor((int)se1, 32);
          U4S8 u;
          u.u[0] = b5 ? w0 : pk[ms][4 * kp];
          u.u[1] = b5 ? w1 : pk[ms][4 * kp + 1];
          u.u[2] = b5 ? pk[ms][4 * kp + 2] : w0;
          u.u[3] = b5 ? pk[ms][4 * kp + 3] : w1;
          short8 pb = u.s8;
          const int kst = (kb >> 4) + ms * 2 + kp;  // key chunk within 128
          short8 v0 = *(const short8*)&Vs[buf][l5][kst * 16 + b5 * 8];
          short8 v1 = *(const short8*)&Vs[buf][32 + l5][kst * 16 + b5 * 8];
          O[0] = __builtin_amdgcn_mfma_f32_32x32x16_bf16(v0, pb, O[0], 0, 0, 0);
          O[1] = __builtin_amdgcn_mfma_f32_32x32x16_bf16(v1, pb, O[1], 0, 0, 0);
          Lacc = __builtin_amdgcn_mfma_f32_32x32x16_bf16(onesA, pb, Lacc, 0, 0, 0);
        }
      }
    }
  }

  float inv = 1.0f / Lacc[0];
  int qrow = q0 + l5;
  unsigned short* op = ctx + (size_t)(b * LL + qrow) * 512 + h * 64;
#pragma unroll
  for (int ds = 0; ds < 2; ds++) {
#pragma unroll
    for (int g = 0; g < 4; g++) {
      uint2 w;
      w.x = pack_bf16(O[ds][4 * g] * inv, O[ds][4 * g + 1] * inv);
      w.y = pack_bf16(O[ds][4 * g + 2] * inv, O[ds][4 * g + 3] * inv);
      *(uint2*)(op + ds * 32 + 8 * g + 4 * b5) = w;
    }
  }
}

extern "C" void kernel_launch(void* const* d_in, const int* in_sizes, int n_in,
                              void* d_out, int out_size, void* d_ws, size_t ws_size,
                              hipStream_t stream) {
  const float* x_in = (const float*)d_in[0];
  const float* pcos = (const float*)d_in[1];
  const float* psin = (const float*)d_in[2];
  const float* amask = (const float*)d_in[3];
  const float* Wq = (const float*)d_in[4];
  const float* Wk = (const float*)d_in[5];
  const float* Wv = (const float*)d_in[6];
  const float* Wo = (const float*)d_in[7];
  const float* W1 = (const float*)d_in[8];
  const float* W2 = (const float*)d_in[9];
  const float* ln1w = (const float*)d_in[10];
  const float* ln1b = (const float*)d_in[11];
  const float* ln2w = (const float*)d_in[12];
  const float* ln2b = (const float*)d_in[13];
  const float* lnfw = (const float*)d_in[14];
  const float* lnfb = (const float*)d_in[15];

  const int M = BB * LL;  // 8192
  char* p = (char*)d_ws;
  float* x_ws = (float*)p;                  p += (size_t)M * DD * 4;
  unsigned short* xn = (unsigned short*)p;  p += (size_t)M * DD * 2;
  unsigned short* qkv = (unsigned short*)p; p += (size_t)M * 1536 * 2;
  unsigned short* vtb = (unsigned short*)p; p += (size_t)M * DD * 2;
  unsigned short* cb = (unsigned short*)p;  p += (size_t)M * DD * 2;
  unsigned short* wts = (unsigned short*)p;
  unsigned short* gb = vtb;  // vtb dead after attn; reused for SwiGLU output

  const size_t LW = 786432 + 262144 + 524288 + 262144;
  TJobs jobs;
  for (int i = 0; i < NLAYER; i++) {
    unsigned short* wl = wts + i * LW;
    jobs.j[i * 6 + 0] = {Wq + (size_t)i * 262144, wl + 0, 512, 0};
    jobs.j[i * 6 + 1] = {Wk + (size_t)i * 262144, wl + 262144, 512, 0};
    jobs.j[i * 6 + 2] = {Wv + (size_t)i * 262144, wl + 524288, 512, 0};
    jobs.j[i * 6 + 3] = {Wo + (size_t)i * 262144, wl + 786432, 512, 0};
    jobs.j[i * 6 + 4] = {W1 + (size_t)i * 524288, wl + 1048576, 1024, 1};
    jobs.j[i * 6 + 5] = {W2 + (size_t)i * 262144, wl + 1572864, 512, 0};
  }
  transpose_all_kernel<<<dim3(32, 16, 12), 256, 0, stream>>>(jobs);

  for (int i = 0; i < NLAYER; i++) {
    unsigned short* wl = wts + i * LW;
    const float* xin = (i == 0) ? x_in : x_ws;
    ln_kernel<<<M, 256, 0, stream>>>(xin, ln1w + i * DD, ln1b + i * DD, xn, nullptr);
    gemm128_kernel<<<dim3(12, 64), 256, 0, stream>>>(xn, wl + 0, nullptr, qkv, nullptr, M, 1536, 512, vtb, pcos, psin);
    attn_kernel<<<dim3(LL / 128, HH, BB), 256, 0, stream>>>(qkv, vtb, amask, cb);
    gemm64n_kernel<<<dim3(8, 64), 256, 0, stream>>>(cb, wl + 786432, x_ws, xin, M, 512, 512);
    ln_kernel<<<M, 256, 0, stream>>>(x_ws, ln2w + i * DD, ln2b + i * DD, xn, nullptr);
    gemm_swiglu_kernel<<<dim3(8, 64), 256, 0, stream>>>(xn, wl + 1048576, gb, M, 1024, 512);
    gemm64n_kernel<<<dim3(8, 64), 256, 0, stream>>>(gb, wl + 1572864, x_ws, x_ws, M, 512, 512);
  }
  ln_kernel<<<M, 256, 0, stream>>>(x_ws, lnfw, lnfb, nullptr, (float*)d_out);
}

// Round 8
// 483.833 us; speedup vs baseline: 1.2176x; 1.2176x over previous
//
#include <hip/hip_runtime.h>

#define BB 4
#define LL 2048
#define DD 512
#define HH 8
#define NLAYER 2

typedef __attribute__((ext_vector_type(8))) short short8;
typedef __attribute__((ext_vector_type(4))) float floatx4;
typedef __attribute__((ext_vector_type(16))) float floatx16;

union U4S8 { uint4 u4; short8 s8; unsigned int u[4]; };

__device__ __forceinline__ unsigned short f2bf(float f) {
  unsigned int u = __float_as_uint(f);
  u += 0x7fffu + ((u >> 16) & 1u);
  return (unsigned short)(u >> 16);
}
__device__ __forceinline__ float bf2f(unsigned short s) {
  return __uint_as_float(((unsigned int)s) << 16);
}
// pack two fp32 -> bf16 pair, round-half-up
__device__ __forceinline__ unsigned int pack_bf16(float a0, float a1) {
  unsigned int u0 = __float_as_uint(a0) + 0x8000u;
  unsigned int u1 = __float_as_uint(a1) + 0x8000u;
  return __builtin_amdgcn_perm(u1, u0, 0x07060302u);
}
// truncating pack (1 op); bias cancels when lsum uses same truncated values
__device__ __forceinline__ unsigned int pack_bf16_trunc(float a0, float a1) {
  return __builtin_amdgcn_perm(__float_as_uint(a1), __float_as_uint(a0), 0x07060302u);
}
__device__ __forceinline__ float fast_exp2(float x) {
#if __has_builtin(__builtin_amdgcn_exp2f)
  return __builtin_amdgcn_exp2f(x);
#else
  return exp2f(x);
#endif
}
__device__ __forceinline__ float fast_exp(float x) {
  return fast_exp2(x * 1.442695040888963f);
}

// ---------------- batched weight transpose fp32 (512 x C) -> bf16 (C x R) ----------------
struct TJob { const float* src; unsigned short* dst; int C; int il; };
struct TJobs { TJob j[12]; };

__global__ __launch_bounds__(256) void transpose_all_kernel(TJobs jobs) {
  TJob jb = jobs.j[blockIdx.z];
  int c0 = blockIdx.x * 32;
  if (c0 >= jb.C) return;
  const int R = 512;
  __shared__ float t[32][33];
  int r0 = blockIdx.y * 32;
#pragma unroll
  for (int i = 0; i < 4; i++) {
    int idx = threadIdx.x + i * 256;
    t[idx >> 5][idx & 31] = jb.src[(size_t)(r0 + (idx >> 5)) * jb.C + c0 + (idx & 31)];
  }
  __syncthreads();
#pragma unroll
  for (int i = 0; i < 4; i++) {
    int idx = threadIdx.x + i * 256;
    int cc = idx >> 5, rr = idx & 31;
    int c = c0 + cc;
    int orow = jb.il ? ((c < 512) ? 2 * c : 2 * (c - 512) + 1) : c;
    jb.dst[(size_t)orow * R + r0 + rr] = f2bf(t[rr][cc]);
  }
}

// ---------------- LayerNorm (D=512), block per row ----------------
__global__ __launch_bounds__(256) void ln_kernel(
    const float* __restrict__ x, const float* __restrict__ w, const float* __restrict__ b,
    unsigned short* __restrict__ outB, float* __restrict__ outF) {
  int row = blockIdx.x;
  const float* xr = x + (size_t)row * DD;
  int tid = threadIdx.x;
  float2 v = *(const float2*)(xr + tid * 2);
  float s = v.x + v.y;
  float ss = v.x * v.x + v.y * v.y;
#pragma unroll
  for (int off = 1; off < 64; off <<= 1) {
    s += __shfl_xor(s, off);
    ss += __shfl_xor(ss, off);
  }
  __shared__ float red[2][4];
  int wave = tid >> 6, lane = tid & 63;
  if (lane == 0) { red[0][wave] = s; red[1][wave] = ss; }
  __syncthreads();
  s = red[0][0] + red[0][1] + red[0][2] + red[0][3];
  ss = red[1][0] + red[1][1] + red[1][2] + red[1][3];
  float mu = s * (1.0f / DD);
  float var = ss * (1.0f / DD) - mu * mu;
  float inv = rsqrtf(var + 1e-5f);
#pragma unroll
  for (int j = 0; j < 2; j++) {
    int c = tid * 2 + j;
    float val = (((j == 0) ? v.x : v.y) - mu) * inv * w[c] + b[c];
    if (outB) outB[(size_t)row * DD + c] = f2bf(val);
    if (outF) outF[(size_t)row * DD + c] = val;
  }
}

// ---------------- GEMM: C[MxN] = A[MxK](bf16) * Bt[NxK](bf16)^T ----------------
// 128x128 tile, BK=32, global_load_lds(16B) with XOR-granule swizzle (m97-style).
// QKV mode (vtp != null, N=1536): n0>=1024 tiles (V) stored TRANSPOSED to vtp;
// n0<1024 tiles (Q,K) get RoPE applied in-register ((d,d+32) = reg pairs (j,j+2));
// Q additionally pre-scaled by 0.125*log2e for the attn exp2 path.
__global__ __launch_bounds__(256) void gemm128_kernel(
    const unsigned short* __restrict__ A, const unsigned short* __restrict__ Bt,
    float* __restrict__ outF, unsigned short* __restrict__ outB,
    const float* __restrict__ res, int M, int N, int K,
    unsigned short* __restrict__ vtp,
    const float* __restrict__ pcos, const float* __restrict__ psin) {
  __shared__ alignas(16) unsigned short As[128 * 32];
  __shared__ alignas(16) unsigned short Bs[128 * 32];
  const int tid = threadIdx.x;
  const int wave = tid >> 6, lane = tid & 63;
  const int l16 = lane & 15, quad = lane >> 4;
  const int wm = wave & 1, wn = wave >> 1;
  const int m0 = blockIdx.y * 128, n0 = blockIdx.x * 128;

  floatx4 acc[4][4];
#pragma unroll
  for (int i = 0; i < 4; i++)
#pragma unroll
    for (int j = 0; j < 4; j++)
#pragma unroll
      for (int r = 0; r < 4; r++) acc[i][j][r] = 0.f;

  const int grow = lane >> 2;
  const int gg = lane & 3;

  for (int kt = 0; kt < K; kt += 32) {
#pragma unroll
    for (int i = 0; i < 2; i++) {
      int rb = (wave * 2 + i) * 16;
      int row = rb + grow;
      int gsw = gg ^ (row & 3);
      const unsigned short* srcA = A + (size_t)(m0 + row) * K + kt + gsw * 8;
      const unsigned short* srcB = Bt + (size_t)(n0 + row) * K + kt + gsw * 8;
      __builtin_amdgcn_global_load_lds(
          (const __attribute__((address_space(1))) unsigned int*)srcA,
          (__attribute__((address_space(3))) unsigned int*)(As + rb * 32), 16, 0, 0);
      __builtin_amdgcn_global_load_lds(
          (const __attribute__((address_space(1))) unsigned int*)srcB,
          (__attribute__((address_space(3))) unsigned int*)(Bs + rb * 32), 16, 0, 0);
    }
    __syncthreads();
    short8 af[4], bf[4];
#pragma unroll
    for (int i = 0; i < 4; i++) {
      int rowa = wm * 64 + i * 16 + l16;
      af[i] = *(const short8*)&As[rowa * 32 + (quad ^ (rowa & 3)) * 8];
      int rowb = wn * 64 + i * 16 + l16;
      bf[i] = *(const short8*)&Bs[rowb * 32 + (quad ^ (rowb & 3)) * 8];
    }
#pragma unroll
    for (int i = 0; i < 4; i++)
#pragma unroll
      for (int j = 0; j < 4; j++)
        acc[i][j] = __builtin_amdgcn_mfma_f32_16x16x32_bf16(af[i], bf[j], acc[i][j], 0, 0, 0);
    __syncthreads();
  }
  if (vtp && n0 >= 1024) {
    // transposed V store: 4 consecutive seq rows per 8B chunk, same d
#pragma unroll
    for (int i = 0; i < 4; i++)
#pragma unroll
      for (int j = 0; j < 4; j++) {
        int cg = (n0 - 1024) + wn * 64 + j * 16 + l16;  // 0..511
        int hh = cg >> 6, dd = cg & 63;
        int seq0 = m0 + wm * 64 + i * 16 + quad * 4;
        int bI = seq0 >> 11, ls = seq0 & 2047;
        unsigned short* dst = vtp + ((size_t)(bI * 8 + hh) * 64 + dd) * 2048 + ls;
        uint2 w;
        w.x = pack_bf16(acc[i][j][0], acc[i][j][1]);
        w.y = pack_bf16(acc[i][j][2], acc[i][j][3]);
        *(uint2*)dst = w;
      }
    return;
  }
  if (vtp) {
    // RoPE on Q (n0<512, also pre-scaled) and K (512<=n0<1024)
    const float QSCALE = 0.125f * 1.442695040888963f;
    const float osc = (n0 < 512) ? QSCALE : 1.0f;
#pragma unroll
    for (int i = 0; i < 4; i++)
#pragma unroll
      for (int r = 0; r < 4; r++) {
        int row = m0 + wm * 64 + i * 16 + quad * 4 + r;
        int t = row & 2047;
        const float* cr = pcos + (size_t)t * 512;
        const float* sr = psin + (size_t)t * 512;
#pragma unroll
        for (int jj = 0; jj < 2; jj++) {
          int colL = n0 + wn * 64 + jj * 16 + l16;
          int cL = colL & 511, cH = cL + 32;
          float aL = acc[i][jj][r], aH = acc[i][jj + 2][r];
          float outL = (aL * cr[cL] - aH * sr[cL]) * osc;
          float outH = (aH * cr[cH] + aL * sr[cH]) * osc;
          size_t base = (size_t)row * N + colL;
          outB[base] = f2bf(outL);
          outB[base + 32] = f2bf(outH);
        }
      }
    return;
  }
#pragma unroll
  for (int i = 0; i < 4; i++)
#pragma unroll
    for (int j = 0; j < 4; j++)
#pragma unroll
      for (int r = 0; r < 4; r++) {
        int row = m0 + wm * 64 + i * 16 + quad * 4 + r;
        int col = n0 + wn * 64 + j * 16 + l16;
        size_t idx = (size_t)row * N + col;
        float val = acc[i][j][r];
        if (res) val += res[idx];
        if (outF) outF[idx] = val;
        if (outB) outB[idx] = f2bf(val);
      }
}

// ---------------- GEMM 128x64 tile (for N=512 outputs: grid 512 -> 2 blocks/CU) ----------------
__global__ __launch_bounds__(256) void gemm64n_kernel(
    const unsigned short* __restrict__ A, const unsigned short* __restrict__ Bt,
    float* __restrict__ outF, const float* __restrict__ res, int M, int N, int K) {
  __shared__ alignas(16) unsigned short As[128 * 32];
  __shared__ alignas(16) unsigned short Bs[64 * 32];
  const int tid = threadIdx.x;
  const int wave = tid >> 6, lane = tid & 63;
  const int l16 = lane & 15, quad = lane >> 4;
  const int m0 = blockIdx.y * 128, n0 = blockIdx.x * 64;

  floatx4 acc[2][4];
#pragma unroll
  for (int i = 0; i < 2; i++)
#pragma unroll
    for (int j = 0; j < 4; j++)
#pragma unroll
      for (int r = 0; r < 4; r++) acc[i][j][r] = 0.f;

  const int grow = lane >> 2;
  const int gg = lane & 3;

  for (int kt = 0; kt < K; kt += 32) {
#pragma unroll
    for (int i = 0; i < 3; i++) {
      int id = wave * 3 + i;
      if (id < 8) {
        int rb = id * 16;
        int row = rb + grow;
        int gsw = gg ^ (row & 3);
        const unsigned short* srcA = A + (size_t)(m0 + row) * K + kt + gsw * 8;
        __builtin_amdgcn_global_load_lds(
            (const __attribute__((address_space(1))) unsigned int*)srcA,
            (__attribute__((address_space(3))) unsigned int*)(As + rb * 32), 16, 0, 0);
      } else {
        int rb = (id - 8) * 16;
        int row = rb + grow;
        int gsw = gg ^ (row & 3);
        const unsigned short* srcB = Bt + (size_t)(n0 + row) * K + kt + gsw * 8;
        __builtin_amdgcn_global_load_lds(
            (const __attribute__((address_space(1))) unsigned int*)srcB,
            (__attribute__((address_space(3))) unsigned int*)(Bs + rb * 32), 16, 0, 0);
      }
    }
    __syncthreads();
    short8 af[2], bfr[4];
#pragma unroll
    for (int i = 0; i < 2; i++) {
      int rowa = wave * 32 + i * 16 + l16;
      af[i] = *(const short8*)&As[rowa * 32 + (quad ^ (rowa & 3)) * 8];
    }
#pragma unroll
    for (int j = 0; j < 4; j++) {
      int rowb = j * 16 + l16;
      bfr[j] = *(const short8*)&Bs[rowb * 32 + (quad ^ (rowb & 3)) * 8];
    }
#pragma unroll
    for (int i = 0; i < 2; i++)
#pragma unroll
      for (int j = 0; j < 4; j++)
        acc[i][j] = __builtin_amdgcn_mfma_f32_16x16x32_bf16(af[i], bfr[j], acc[i][j], 0, 0, 0);
    __syncthreads();
  }
#pragma unroll
  for (int i = 0; i < 2; i++)
#pragma unroll
    for (int j = 0; j < 4; j++)
#pragma unroll
      for (int r = 0; r < 4; r++) {
        int row = m0 + wave * 32 + i * 16 + quad * 4 + r;
        int col = n0 + j * 16 + l16;
        size_t idx = (size_t)row * N + col;
        float val = acc[i][j][r];
        if (res) val += res[idx];
        outF[idx] = val;
      }
}

// ---------------- GEMM + fused SwiGLU epilogue ----------------
__global__ __launch_bounds__(256) void gemm_swiglu_kernel(
    const unsigned short* __restrict__ A, const unsigned short* __restrict__ Bt,
    unsigned short* __restrict__ gout, int M, int N, int K) {
  __shared__ alignas(16) unsigned short As[128 * 32];
  __shared__ alignas(16) unsigned short Bs[128 * 32];
  const int tid = threadIdx.x;
  const int wave = tid >> 6, lane = tid & 63;
  const int l16 = lane & 15, quad = lane >> 4;
  const int wm = wave & 1, wn = wave >> 1;
  const int m0 = blockIdx.y * 128, n0 = blockIdx.x * 128;
  floatx4 acc[4][4];
#pragma unroll
  for (int i = 0; i < 4; i++)
#pragma unroll
    for (int j = 0; j < 4; j++)
#pragma unroll
      for (int r = 0; r < 4; r++) acc[i][j][r] = 0.f;
  const int grow = lane >> 2;
  const int gg = lane & 3;
  for (int kt = 0; kt < K; kt += 32) {
#pragma unroll
    for (int i = 0; i < 2; i++) {
      int rb = (wave * 2 + i) * 16;
      int row = rb + grow;
      int gsw = gg ^ (row & 3);
      const unsigned short* srcA = A + (size_t)(m0 + row) * K + kt + gsw * 8;
      const unsigned short* srcB = Bt + (size_t)(n0 + row) * K + kt + gsw * 8;
      __builtin_amdgcn_global_load_lds(
          (const __attribute__((address_space(1))) unsigned int*)srcA,
          (__attribute__((address_space(3))) unsigned int*)(As + rb * 32), 16, 0, 0);
      __builtin_amdgcn_global_load_lds(
          (const __attribute__((address_space(1))) unsigned int*)srcB,
          (__attribute__((address_space(3))) unsigned int*)(Bs + rb * 32), 16, 0, 0);
    }
    __syncthreads();
    short8 af[4], bf[4];
#pragma unroll
    for (int i = 0; i < 4; i++) {
      int rowa = wm * 64 + i * 16 + l16;
      af[i] = *(const short8*)&As[rowa * 32 + (quad ^ (rowa & 3)) * 8];
      int rowb = wn * 64 + i * 16 + l16;
      bf[i] = *(const short8*)&Bs[rowb * 32 + (quad ^ (rowb & 3)) * 8];
    }
#pragma unroll
    for (int i = 0; i < 4; i++)
#pragma unroll
      for (int j = 0; j < 4; j++)
        acc[i][j] = __builtin_amdgcn_mfma_f32_16x16x32_bf16(af[i], bf[j], acc[i][j], 0, 0, 0);
    __syncthreads();
  }
  const int Nh = N >> 1;
#pragma unroll
  for (int i = 0; i < 4; i++)
#pragma unroll
    for (int j = 0; j < 4; j++)
#pragma unroll
      for (int r = 0; r < 4; r++) {
        float val = acc[i][j][r];
        float part = __shfl_xor(val, 1);
        float x1 = (l16 & 1) ? part : val;
        float x2 = (l16 & 1) ? val : part;
        float g = x1 / (1.f + fast_exp(-x1)) * x2;
        if (!(l16 & 1)) {
          int row = m0 + wm * 64 + i * 16 + quad * 4 + r;
          int gcol = (n0 + wn * 64 + j * 16 + l16) >> 1;
          gout[(size_t)row * Nh + gcol] = f2bf(g);
        }
      }
}

// ---------------- attention: S^T = K Q^T via 32x32x16 MFMA ----------------
// Round-4 proven structure: KT=64, double-buffered, 4 waves x 32 q.
// Q comes pre-scaled by 0.125*log2e (gemm epilogue); lsum via ones-MFMA.
__global__ __launch_bounds__(256, 2) void attn_kernel(
    const unsigned short* __restrict__ qkv, const unsigned short* __restrict__ vtp,
    const float* __restrict__ mask, unsigned short* __restrict__ ctx) {
  __shared__ alignas(16) unsigned short Ks[2][64][72];
  __shared__ alignas(16) unsigned short Vs[2][64][72];
  const int tid = threadIdx.x;
  const int wave = tid >> 6, lane = tid & 63;
  const int l5 = lane & 31, b5 = lane >> 5;
  const int b = blockIdx.z, h = blockIdx.y;
  const int q0 = blockIdx.x * 128 + wave * 32;
  const int bh = b * 8 + h;

  short8 qf[4];
  {
    const unsigned short* qp = qkv + (size_t)(b * LL + q0 + l5) * 1536 + h * 64 + b5 * 8;
#pragma unroll
    for (int t = 0; t < 4; t++) {
      U4S8 u;
      u.u4 = *(const uint4*)(qp + t * 16);
      qf[t] = u.s8;
    }
  }
  short8 bones = {0, 0, 0, 0, 0, 0, 0, 0};
  if (b5 == 0) bones[0] = (short)0x3F80;
  short8 onesA;
#pragma unroll
  for (int e = 0; e < 8; e++) onesA[e] = (short)0x3F80;

  floatx16 O[2], Lacc;
#pragma unroll
  for (int a = 0; a < 2; a++)
#pragma unroll
    for (int r = 0; r < 16; r++) O[a][r] = 0.f;
#pragma unroll
  for (int r = 0; r < 16; r++) Lacc[r] = 0.f;

  const int srow = tid >> 2, sc = (tid & 3) * 16;
  const unsigned short* kbase = qkv + (size_t)(b * LL + srow) * 1536 + 512 + h * 64 + sc;
  const unsigned short* vbase = vtp + (size_t)(bh * 64 + srow) * 2048 + sc;

  uint4 kr0 = *(const uint4*)kbase;
  uint4 kr1 = *(const uint4*)(kbase + 8);
  uint4 vr0 = *(const uint4*)vbase;
  uint4 vr1 = *(const uint4*)(vbase + 8);

  for (int t0 = 0, it = 0; t0 < LL; t0 += 64, it++) {
    const int buf = it & 1;
    *(uint4*)&Ks[buf][srow][sc] = kr0;
    *(uint4*)&Ks[buf][srow][sc + 8] = kr1;
    *(uint4*)&Vs[buf][srow][sc] = vr0;
    *(uint4*)&Vs[buf][srow][sc + 8] = vr1;
    __syncthreads();
    if (t0 + 64 < LL) {
      const unsigned short* kn = kbase + (size_t)(t0 + 64) * 1536;
      const unsigned short* vn = vbase + t0 + 64;
      kr0 = *(const uint4*)kn;
      kr1 = *(const uint4*)(kn + 8);
      vr0 = *(const uint4*)vn;
      vr1 = *(const uint4*)(vn + 8);
    }
    float mk0 = mask[b * LL + t0 + l5];
    float mk1 = mask[b * LL + t0 + 32 + l5];
    short8 kf[2][4];
#pragma unroll
    for (int ms = 0; ms < 2; ms++)
#pragma unroll
      for (int t = 0; t < 4; t++)
        kf[ms][t] = *(const short8*)&Ks[buf][ms * 32 + l5][t * 16 + b5 * 8];

    floatx16 s0, s1;
#pragma unroll
    for (int r = 0; r < 16; r++) { s0[r] = 0.f; s1[r] = 0.f; }
#pragma unroll
    for (int t = 0; t < 4; t++) {
      s0 = __builtin_amdgcn_mfma_f32_32x32x16_bf16(kf[0][t], qf[t], s0, 0, 0, 0);
      s1 = __builtin_amdgcn_mfma_f32_32x32x16_bf16(kf[1][t], qf[t], s1, 0, 0, 0);
    }
    if (__any(mk0 != 0.0f || mk1 != 0.0f)) {
      short8 am0 = {0, 0, 0, 0, 0, 0, 0, 0}, am1 = {0, 0, 0, 0, 0, 0, 0, 0};
      if (b5 == 0) {
        am0[0] = (short)f2bf(1.442695040888963f * mk0);
        am1[0] = (short)f2bf(1.442695040888963f * mk1);
      }
      s0 = __builtin_amdgcn_mfma_f32_32x32x16_bf16(am0, bones, s0, 0, 0, 0);
      s1 = __builtin_amdgcn_mfma_f32_32x32x16_bf16(am1, bones, s1, 0, 0, 0);
    }

    unsigned int pk[2][8];
#pragma unroll
    for (int i = 0; i < 8; i++) {
      pk[0][i] = pack_bf16_trunc(fast_exp2(s0[2 * i]), fast_exp2(s0[2 * i + 1]));
      pk[1][i] = pack_bf16_trunc(fast_exp2(s1[2 * i]), fast_exp2(s1[2 * i + 1]));
    }
#pragma unroll
    for (int ms = 0; ms < 2; ms++) {
#pragma unroll
      for (int kp = 0; kp < 2; kp++) {
        unsigned int se0 = b5 ? pk[ms][4 * kp] : pk[ms][4 * kp + 2];
        unsigned int se1 = b5 ? pk[ms][4 * kp + 1] : pk[ms][4 * kp + 3];
        unsigned int w0 = (unsigned int)__shfl_xor((int)se0, 32);
        unsigned int w1 = (unsigned int)__shfl_xor((int)se1, 32);
        U4S8 u;
        u.u[0] = b5 ? w0 : pk[ms][4 * kp];
        u.u[1] = b5 ? w1 : pk[ms][4 * kp + 1];
        u.u[2] = b5 ? pk[ms][4 * kp + 2] : w0;
        u.u[3] = b5 ? pk[ms][4 * kp + 3] : w1;
        short8 pb = u.s8;
        const int kst = ms * 2 + kp;
        short8 v0 = *(const short8*)&Vs[buf][l5][kst * 16 + b5 * 8];
        short8 v1 = *(const short8*)&Vs[buf][32 + l5][kst * 16 + b5 * 8];
        O[0] = __builtin_amdgcn_mfma_f32_32x32x16_bf16(v0, pb, O[0], 0, 0, 0);
        O[1] = __builtin_amdgcn_mfma_f32_32x32x16_bf16(v1, pb, O[1], 0, 0, 0);
        Lacc = __builtin_amdgcn_mfma_f32_32x32x16_bf16(onesA, pb, Lacc, 0, 0, 0);
      }
    }
  }

  float inv = 1.0f / Lacc[0];
  int qrow = q0 + l5;
  unsigned short* op = ctx + (size_t)(b * LL + qrow) * 512 + h * 64;
#pragma unroll
  for (int ds = 0; ds < 2; ds++) {
#pragma unroll
    for (int g = 0; g < 4; g++) {
      uint2 w;
      w.x = pack_bf16(O[ds][4 * g] * inv, O[ds][4 * g + 1] * inv);
      w.y = pack_bf16(O[ds][4 * g + 2] * inv, O[ds][4 * g + 3] * inv);
      *(uint2*)(op + ds * 32 + 8 * g + 4 * b5) = w;
    }
  }
}

extern "C" void kernel_launch(void* const* d_in, const int* in_sizes, int n_in,
                              void* d_out, int out_size, void* d_ws, size_t ws_size,
                              hipStream_t stream) {
  const float* x_in = (const float*)d_in[0];
  const float* pcos = (const float*)d_in[1];
  const float* psin = (const float*)d_in[2];
  const float* amask = (const float*)d_in[3];
  const float* Wq = (const float*)d_in[4];
  const float* Wk = (const float*)d_in[5];
  const float* Wv = (const float*)d_in[6];
  const float* Wo = (const float*)d_in[7];
  const float* W1 = (const float*)d_in[8];
  const float* W2 = (const float*)d_in[9];
  const float* ln1w = (const float*)d_in[10];
  const float* ln1b = (const float*)d_in[11];
  const float* ln2w = (const float*)d_in[12];
  const float* ln2b = (const float*)d_in[13];
  const float* lnfw = (const float*)d_in[14];
  const float* lnfb = (const float*)d_in[15];

  const int M = BB * LL;  // 8192
  char* p = (char*)d_ws;
  float* x_ws = (float*)p;                  p += (size_t)M * DD * 4;
  unsigned short* xn = (unsigned short*)p;  p += (size_t)M * DD * 2;
  unsigned short* qkv = (unsigned short*)p; p += (size_t)M * 1536 * 2;
  unsigned short* vtb = (unsigned short*)p; p += (size_t)M * DD * 2;
  unsigned short* cb = (unsigned short*)p;  p += (size_t)M * DD * 2;
  unsigned short* wts = (unsigned short*)p;
  unsigned short* gb = vtb;  // vtb dead after attn; reused for SwiGLU output

  const size_t LW = 786432 + 262144 + 524288 + 262144;
  TJobs jobs;
  for (int i = 0; i < NLAYER; i++) {
    unsigned short* wl = wts + i * LW;
    jobs.j[i * 6 + 0] = {Wq + (size_t)i * 262144, wl + 0, 512, 0};
    jobs.j[i * 6 + 1] = {Wk + (size_t)i * 262144, wl + 262144, 512, 0};
    jobs.j[i * 6 + 2] = {Wv + (size_t)i * 262144, wl + 524288, 512, 0};
    jobs.j[i * 6 + 3] = {Wo + (size_t)i * 262144, wl + 786432, 512, 0};
    jobs.j[i * 6 + 4] = {W1 + (size_t)i * 524288, wl + 1048576, 1024, 1};
    jobs.j[i * 6 + 5] = {W2 + (size_t)i * 262144, wl + 1572864, 512, 0};
  }
  transpose_all_kernel<<<dim3(32, 16, 12), 256, 0, stream>>>(jobs);

  for (int i = 0; i < NLAYER; i++) {
    unsigned short* wl = wts + i * LW;
    const float* xin = (i == 0) ? x_in : x_ws;
    ln_kernel<<<M, 256, 0, stream>>>(xin, ln1w + i * DD, ln1b + i * DD, xn, nullptr);
    gemm128_kernel<<<dim3(12, 64), 256, 0, stream>>>(xn, wl + 0, nullptr, qkv, nullptr, M, 1536, 512, vtb, pcos, psin);
    attn_kernel<<<dim3(LL / 128, HH, BB), 256, 0, stream>>>(qkv, vtb, amask, cb);
    gemm64n_kernel<<<dim3(8, 64), 256, 0, stream>>>(cb, wl + 786432, x_ws, xin, M, 512, 512);
    ln_kernel<<<M, 256, 0, stream>>>(x_ws, ln2w + i * DD, ln2b + i * DD, xn, nullptr);
    gemm_swiglu_kernel<<<dim3(8, 64), 256, 0, stream>>>(xn, wl + 1048576, gb, M, 1024, 512);
    gemm64n_kernel<<<dim3(8, 64), 256, 0, stream>>>(gb, wl + 1572864, x_ws, x_ws, M, 512, 512);
  }
  ln_kernel<<<M, 256, 0, stream>>>(x_ws, lnfw, lnfb, nullptr, (float*)d_out);
}